// Round 10
// baseline (299.478 us; speedup 1.0000x reference)
//
#include <hip/hip_runtime.h>
#include <hip/hip_bf16.h>
#include <math.h>

#define PN 1024
#define PB 4
#define PC 256
#define PH 8
#define PD 32

typedef __attribute__((ext_vector_type(8))) short bf16x8;
typedef __attribute__((ext_vector_type(4))) float f32x4;

__device__ __forceinline__ unsigned short f2b(float f) {
    unsigned int u = __builtin_bit_cast(unsigned int, f);
    unsigned int r = (u + 0x7fffu + ((u >> 16) & 1u)) >> 16;
    return (unsigned short)r;
}
__device__ __forceinline__ float b2f(unsigned short u) {
    return __builtin_bit_cast(float, ((unsigned int)u) << 16);
}
// load 8 consecutive f32, convert to bf16x8 fragment
__device__ __forceinline__ bf16x8 ldf8(const float* p) {
    float4 u0 = ((const float4*)p)[0];
    float4 u1 = ((const float4*)p)[1];
    bf16x8 r;
    r[0] = (short)f2b(u0.x); r[1] = (short)f2b(u0.y);
    r[2] = (short)f2b(u0.z); r[3] = (short)f2b(u0.w);
    r[4] = (short)f2b(u1.x); r[5] = (short)f2b(u1.y);
    r[6] = (short)f2b(u1.z); r[7] = (short)f2b(u1.w);
    return r;
}

// ---------------------------------------------------------------------------
// Kernel 1: projection via MFMA, f32 inputs converted in-register.
// (byte-identical to round 8)
// ---------------------------------------------------------------------------
__global__ __launch_bounds__(256) void proj_mfma(
    const float* __restrict__ xq, const float* __restrict__ xk, const float* __restrict__ xv,
    const float* __restrict__ wq, const float* __restrict__ wk, const float* __restrict__ wv,
    unsigned short* __restrict__ qb, unsigned short* __restrict__ kb, unsigned short* __restrict__ vt)
{
    const int z = blockIdx.z;
    const float* X = (z == 0) ? xq : (z == 1) ? xk : xv;
    const float* W = (z == 0) ? wq : (z == 1) ? wk : wv;

    const int row0 = blockIdx.x * 64, col0 = blockIdx.y * 64;
    const int tid = threadIdx.x;
    const int w = tid >> 6, l = tid & 63;
    const int l15 = l & 15, lg = l >> 4;
    const int wm = w >> 1, wn = w & 1;

    f32x4 acc[2][2];
    #pragma unroll
    for (int a = 0; a < 2; a++)
        #pragma unroll
        for (int b = 0; b < 2; b++) acc[a][b] = (f32x4){0.f, 0.f, 0.f, 0.f};

    #pragma unroll
    for (int ks = 0; ks < 8; ks++) {
        int koff = ks * 32 + lg * 8;
        bf16x8 a0 = ldf8(X + (size_t)(row0 + wm * 32 + l15) * 256 + koff);
        bf16x8 a1 = ldf8(X + (size_t)(row0 + wm * 32 + 16 + l15) * 256 + koff);
        bf16x8 b0 = ldf8(W + (size_t)(col0 + wn * 32 + l15) * 256 + koff);
        bf16x8 b1 = ldf8(W + (size_t)(col0 + wn * 32 + 16 + l15) * 256 + koff);
        acc[0][0] = __builtin_amdgcn_mfma_f32_16x16x32_bf16(a0, b0, acc[0][0], 0, 0, 0);
        acc[0][1] = __builtin_amdgcn_mfma_f32_16x16x32_bf16(a0, b1, acc[0][1], 0, 0, 0);
        acc[1][0] = __builtin_amdgcn_mfma_f32_16x16x32_bf16(a1, b0, acc[1][0], 0, 0, 0);
        acc[1][1] = __builtin_amdgcn_mfma_f32_16x16x32_bf16(a1, b1, acc[1][1], 0, 0, 0);
    }

    if (z < 2) {
        #pragma unroll
        for (int as = 0; as < 2; as++) {
            #pragma unroll
            for (int r = 0; r < 4; r++) {
                float ss = acc[as][0][r] * acc[as][0][r] + acc[as][1][r] * acc[as][1][r];
                ss += __shfl_xor(ss, 1);
                ss += __shfl_xor(ss, 2);
                ss += __shfl_xor(ss, 4);
                ss += __shfl_xor(ss, 8);
                float inv = rsqrtf(ss);
                acc[as][0][r] *= inv;
                acc[as][1][r] *= inv;
            }
        }
    }

    #pragma unroll
    for (int as = 0; as < 2; as++) {
        #pragma unroll
        for (int bs = 0; bs < 2; bs++) {
            #pragma unroll
            for (int r = 0; r < 4; r++) {
                int Xrow = row0 + wm * 32 + as * 16 + lg * 4 + r;
                int c = col0 + wn * 32 + bs * 16 + l15;
                int n = Xrow >> 2, bb = Xrow & 3, hh = c >> 5, dd = c & 31;
                unsigned short val = f2b(acc[as][bs][r]);
                if (z == 0)      qb[((size_t)((bb * 8 + hh) * 1024 + n)) * 32 + dd] = val;
                else if (z == 1) kb[((size_t)((bb * 8 + hh) * 1024 + n)) * 32 + dd] = val;
                else             vt[((size_t)((bb * 8 + hh) * 32 + dd)) * 1024 + n] = val;
            }
        }
    }
}

// ---------------------------------------------------------------------------
// Kernel 2: position bias [H,N,N] via MFMA with bf16 hi/lo split (no LDS).
// Block = 256 threads = 4 waves; each wave does one 16x16 tile:
// rows = 16 m values, cols = 8 heads (cols 8..15 discarded).
// Lane (l15,lg): A-frag rows l15 (m), k-slice lg*8..+8 -> 4 (sin,cos) pairs
// per K-step, generated in-register. B-frag rows l15 (=h), same k-slice from
// pos_w. pe = Ahi*Bhi + Alo*Bhi + Ahi*Blo (drop lo*lo, ~2e-6/term).
// K-order: u32 slot u = p*8+i holds (sin(pm[p]*inv[i]), cos(...)).
// p = s*2 + (lg>>1), i = (lg&1)*4 + c  -- all selects static-indexed.
// ---------------------------------------------------------------------------
__global__ __launch_bounds__(256) void bias_kernel(
    const float* __restrict__ qbx, const float* __restrict__ kbx,
    const float* __restrict__ pw, const float* __restrict__ pb,
    unsigned short* __restrict__ biasb)
{
    const int tid = threadIdx.x;
    const int w = tid >> 6, l = tid & 63;
    const int l15 = l & 15, lg = l >> 4;
    const int n = blockIdx.y;
    const int mbase = blockIdx.x * 64 + w * 16;
    const int m = mbase + l15;
    const int lgh = lg >> 1, lgl = lg & 1;

    // ---- pm[4] for (n, m) ----
    float4 qx = ((const float4*)qbx)[n];
    float4 kx = ((const float4*)kbx)[m];
    float cx = 0.5f * (qx.x + qx.z), cy = 0.5f * (qx.y + qx.w);
    float bw = qx.z - qx.x + 1.0f,   bh = qx.w - qx.y + 1.0f;
    float cxr = 0.5f * (kx.x + kx.z), cyr = 0.5f * (kx.y + kx.w);
    float wr  = kx.z - kx.x + 1.0f,   hr  = kx.w - kx.y + 1.0f;

    float pm[4];
    pm[0] = __logf(fabsf((cx - cxr) / bw) + 1e-3f);
    pm[1] = __logf(fabsf((cy - cyr) / bh) + 1e-3f);
    pm[2] = __logf(bw / wr);
    pm[3] = __logf(bh / hr);

    // freq multipliers 100/1000^(i/8), i = lgl*4 + c (c compile-time)
    const float f_lo[4] = {100.f, 42.1696503f, 17.7827941f, 7.49894209f};
    const float f_hi[4] = {3.16227766f, 1.33352143f, 0.562341325f, 0.237137371f};

    // ---- A fragments (emb hi/lo), B fragments (pos_w hi/lo) ----
    bf16x8 ahi[2], alo[2], bhi[2], blo[2];
    const int h = l15;
    #pragma unroll
    for (int s = 0; s < 2; s++) {
        float pmv = lgh ? pm[s * 2 + 1] : pm[s * 2];
        int p = s * 2 + lgh;
        #pragma unroll
        for (int c = 0; c < 4; c++) {
            float fi = lgl ? f_hi[c] : f_lo[c];
            float a = pmv * fi;
            float sv = __sinf(a), cv = __cosf(a);
            unsigned short sh = f2b(sv), ch = f2b(cv);
            unsigned short sl = f2b(sv - b2f(sh)), cl = f2b(cv - b2f(ch));
            ahi[s][2 * c] = (short)sh; ahi[s][2 * c + 1] = (short)ch;
            alo[s][2 * c] = (short)sl; alo[s][2 * c + 1] = (short)cl;

            float wsv = 0.f, wcv = 0.f;
            if (h < 8) {
                int i = lgl * 4 + c;
                wsv = pw[h * 64 + p * 16 + i];
                wcv = pw[h * 64 + p * 16 + 8 + i];
            }
            unsigned short wsh = f2b(wsv), wch = f2b(wcv);
            unsigned short wsl = f2b(wsv - b2f(wsh)), wcl = f2b(wcv - b2f(wch));
            bhi[s][2 * c] = (short)wsh; bhi[s][2 * c + 1] = (short)wch;
            blo[s][2 * c] = (short)wsl; blo[s][2 * c + 1] = (short)wcl;
        }
    }

    // ---- 6 MFMAs: (Ahi+Alo)*(Bhi+Blo) minus lo*lo ----
    f32x4 acc = (f32x4){0.f, 0.f, 0.f, 0.f};
    #pragma unroll
    for (int s = 0; s < 2; s++) {
        acc = __builtin_amdgcn_mfma_f32_16x16x32_bf16(ahi[s], bhi[s], acc, 0, 0, 0);
        acc = __builtin_amdgcn_mfma_f32_16x16x32_bf16(alo[s], bhi[s], acc, 0, 0, 0);
        acc = __builtin_amdgcn_mfma_f32_16x16x32_bf16(ahi[s], blo[s], acc, 0, 0, 0);
    }

    // ---- epilogue: lane (l15=h<8, lg) holds pe[mrow=lg*4+r][h] ----
    if (l15 < 8) {
        float pbv = pb[l15];
        #pragma unroll
        for (int r = 0; r < 4; r++) {
            int mg = mbase + lg * 4 + r;
            float v = acc[r] + pbv;
            float bv = __logf(fmaxf(v, 0.f) + 1e-6f);
            biasb[((size_t)(l15 * 1024 + n)) * 1024 + mg] = f2b(bv);
        }
    }
}

// ---------------------------------------------------------------------------
// Kernel 3: fused attention (byte-identical to round 8).
// ---------------------------------------------------------------------------
#define SBS 1032   // bf16 elems per Sb row (2064 B, 16B-aligned rows)

__global__ __launch_bounds__(512, 4) void attn_kernel(
    const unsigned short* __restrict__ qb, const unsigned short* __restrict__ kb,
    const unsigned short* __restrict__ vt, const unsigned short* __restrict__ biasb,
    float* __restrict__ out, float* __restrict__ attn_out)
{
    __shared__ unsigned short Sb[16][SBS];        // 33024 B
    __shared__ float part[8][16][17];             // 8704 B

    const int bh = blockIdx.y;
    const int b = bh >> 3, h = bh & 7;
    const int n0 = blockIdx.x * 16;
    const int tid = threadIdx.x;
    const int w = tid >> 6, l = tid & 63;
    const int l15 = l & 15, lg = l >> 4;

    // ---- QK^T: wave w covers keys [w*128, w*128+128) = 8 MFMAs ----
    {
        const int qrow = n0 + l15;
        bf16x8 aq = *(const bf16x8*)(qb + ((size_t)(bh << 10) + qrow) * 32 + lg * 8);
        #pragma unroll
        for (int t = 0; t < 8; ++t) {
            int key = w * 128 + t * 16 + l15;
            bf16x8 bk = *(const bf16x8*)(kb + ((size_t)(bh << 10) + key) * 32 + lg * 8);
            f32x4 acc = (f32x4){0.f, 0.f, 0.f, 0.f};
            acc = __builtin_amdgcn_mfma_f32_16x16x32_bf16(aq, bk, acc, 0, 0, 0);
            #pragma unroll
            for (int r = 0; r < 4; ++r)
                Sb[lg * 4 + r][key] = f2b(acc[r]);
        }
    }
    __syncthreads();

    // ---- softmax + bias + attn write + P(bf16) back to LDS: 2 rows/wave ----
    {
        #pragma unroll
        for (int rr = 0; rr < 2; ++rr) {
            int r = w * 2 + rr;
            float s[16];
            #pragma unroll
            for (int i = 0; i < 16; ++i) s[i] = b2f(Sb[r][l + 64 * i]);
            float mx = s[0];
            #pragma unroll
            for (int i = 1; i < 16; ++i) mx = fmaxf(mx, s[i]);
            #pragma unroll
            for (int off = 32; off > 0; off >>= 1) mx = fmaxf(mx, __shfl_xor(mx, off));
            float e[16], sum = 0.f;
            #pragma unroll
            for (int i = 0; i < 16; ++i) { e[i] = __expf(s[i] - mx); sum += e[i]; }
            #pragma unroll
            for (int off = 32; off > 0; off >>= 1) sum += __shfl_xor(sum, off);
            float invs = 1.f / sum;

            const unsigned short* brow = biasb + ((size_t)(h * 1024 + n0 + r)) * 1024;
            float* arow = attn_out + ((size_t)(bh * 1024 + n0 + r)) * 1024;
            #pragma unroll
            for (int i = 0; i < 16; ++i) {
                int m = l + 64 * i;
                float a = e[i] * invs + b2f(brow[m]);
                arow[m] = a;
                Sb[r][m] = f2b(a);
            }
        }
    }
    __syncthreads();

    // ---- PV: wave = (ds = w>>2, kh = w&3); m-range kh*256..+256 ----
    {
        const int ds = w >> 2, kh = w & 3;
        f32x4 acc = (f32x4){0.f, 0.f, 0.f, 0.f};
        const unsigned short* vrow = vt + ((size_t)(bh * 32 + ds * 16 + l15) << 10);
        const unsigned short* srow = &Sb[l15][0];
        #pragma unroll
        for (int st = 0; st < 8; ++st) {
            int m0 = kh * 256 + st * 32 + lg * 8;
            bf16x8 ap = *(const bf16x8*)(srow + m0);
            bf16x8 bv = *(const bf16x8*)(vrow + m0);
            acc = __builtin_amdgcn_mfma_f32_16x16x32_bf16(ap, bv, acc, 0, 0, 0);
        }
        #pragma unroll
        for (int r = 0; r < 4; ++r) part[w][lg * 4 + r][l15] = acc[r];
    }
    __syncthreads();

    // ---- reduce k-quarters, write out [n][b][c] ----
    {
        int q = tid >> 5, d = tid & 31;
        int ds = d >> 4, d15 = d & 15;
        float v = part[ds * 4 + 0][q][d15] + part[ds * 4 + 1][q][d15]
                + part[ds * 4 + 2][q][d15] + part[ds * 4 + 3][q][d15];
        out[((size_t)(n0 + q) * PB + b) * PC + h * PD + d] = v;
    }
}

// ---------------------------------------------------------------------------
extern "C" void kernel_launch(void* const* d_in, const int* in_sizes, int n_in,
                              void* d_out, int out_size, void* d_ws, size_t ws_size,
                              hipStream_t stream)
{
    const float* query   = (const float*)d_in[0];
    const float* key     = (const float*)d_in[1];
    const float* value   = (const float*)d_in[2];
    const float* q_boxes = (const float*)d_in[3];
    const float* k_boxes = (const float*)d_in[4];
    const float* Wq      = (const float*)d_in[5];
    const float* Wk      = (const float*)d_in[6];
    const float* Wv      = (const float*)d_in[7];
    const float* pos_w   = (const float*)d_in[8];
    const float* pos_b   = (const float*)d_in[9];

    unsigned short* u = (unsigned short*)d_ws;
    unsigned short* qbf  = u;                     // 1048576 [bh][n][d] normalized
    unsigned short* kbf  = qbf + 1048576;         // 1048576 [bh][n][d] normalized
    unsigned short* vtb  = kbf + 1048576;         // 1048576 [bh][d][n]
    unsigned short* bias = vtb + 1048576;         // 8388608 [h][n][m]

    float* out  = (float*)d_out;                  // [N,B,C]
    float* attn = out + (size_t)PN * PB * PC;     // [B,H,N,N]

    proj_mfma<<<dim3(64, 4, 3), 256, 0, stream>>>(query, key, value, Wq, Wk, Wv,
                                                  qbf, kbf, vtb);
    bias_kernel<<<dim3(16, 1024), 256, 0, stream>>>(q_boxes, k_boxes, pos_w, pos_b, bias);
    attn_kernel<<<dim3(64, 32), 512, 0, stream>>>(qbf, kbf, vtb, bias, out, attn);
}

// Round 11
// 234.746 us; speedup vs baseline: 1.2758x; 1.2758x over previous
//
#include <hip/hip_runtime.h>
#include <hip/hip_bf16.h>
#include <math.h>

#define PN 1024
#define PB 4
#define PC 256
#define PH 8
#define PD 32

typedef __attribute__((ext_vector_type(8))) short bf16x8;
typedef __attribute__((ext_vector_type(4))) float f32x4;

__device__ __forceinline__ unsigned short f2b(float f) {
    unsigned int u = __builtin_bit_cast(unsigned int, f);
    unsigned int r = (u + 0x7fffu + ((u >> 16) & 1u)) >> 16;
    return (unsigned short)r;
}
__device__ __forceinline__ float b2f(unsigned short u) {
    return __builtin_bit_cast(float, ((unsigned int)u) << 16);
}
// load 8 consecutive f32, convert to bf16x8 fragment
__device__ __forceinline__ bf16x8 ldf8(const float* p) {
    float4 u0 = ((const float4*)p)[0];
    float4 u1 = ((const float4*)p)[1];
    bf16x8 r;
    r[0] = (short)f2b(u0.x); r[1] = (short)f2b(u0.y);
    r[2] = (short)f2b(u0.z); r[3] = (short)f2b(u0.w);
    r[4] = (short)f2b(u1.x); r[5] = (short)f2b(u1.y);
    r[6] = (short)f2b(u1.z); r[7] = (short)f2b(u1.w);
    return r;
}

// ---------------------------------------------------------------------------
// Kernel 1: projection via MFMA, f32 inputs converted in-register.
// (byte-identical to round 8)
// ---------------------------------------------------------------------------
__global__ __launch_bounds__(256) void proj_mfma(
    const float* __restrict__ xq, const float* __restrict__ xk, const float* __restrict__ xv,
    const float* __restrict__ wq, const float* __restrict__ wk, const float* __restrict__ wv,
    unsigned short* __restrict__ qb, unsigned short* __restrict__ kb, unsigned short* __restrict__ vt)
{
    const int z = blockIdx.z;
    const float* X = (z == 0) ? xq : (z == 1) ? xk : xv;
    const float* W = (z == 0) ? wq : (z == 1) ? wk : wv;

    const int row0 = blockIdx.x * 64, col0 = blockIdx.y * 64;
    const int tid = threadIdx.x;
    const int w = tid >> 6, l = tid & 63;
    const int l15 = l & 15, lg = l >> 4;
    const int wm = w >> 1, wn = w & 1;

    f32x4 acc[2][2];
    #pragma unroll
    for (int a = 0; a < 2; a++)
        #pragma unroll
        for (int b = 0; b < 2; b++) acc[a][b] = (f32x4){0.f, 0.f, 0.f, 0.f};

    #pragma unroll
    for (int ks = 0; ks < 8; ks++) {
        int koff = ks * 32 + lg * 8;
        bf16x8 a0 = ldf8(X + (size_t)(row0 + wm * 32 + l15) * 256 + koff);
        bf16x8 a1 = ldf8(X + (size_t)(row0 + wm * 32 + 16 + l15) * 256 + koff);
        bf16x8 b0 = ldf8(W + (size_t)(col0 + wn * 32 + l15) * 256 + koff);
        bf16x8 b1 = ldf8(W + (size_t)(col0 + wn * 32 + 16 + l15) * 256 + koff);
        acc[0][0] = __builtin_amdgcn_mfma_f32_16x16x32_bf16(a0, b0, acc[0][0], 0, 0, 0);
        acc[0][1] = __builtin_amdgcn_mfma_f32_16x16x32_bf16(a0, b1, acc[0][1], 0, 0, 0);
        acc[1][0] = __builtin_amdgcn_mfma_f32_16x16x32_bf16(a1, b0, acc[1][0], 0, 0, 0);
        acc[1][1] = __builtin_amdgcn_mfma_f32_16x16x32_bf16(a1, b1, acc[1][1], 0, 0, 0);
    }

    if (z < 2) {
        #pragma unroll
        for (int as = 0; as < 2; as++) {
            #pragma unroll
            for (int r = 0; r < 4; r++) {
                float ss = acc[as][0][r] * acc[as][0][r] + acc[as][1][r] * acc[as][1][r];
                ss += __shfl_xor(ss, 1);
                ss += __shfl_xor(ss, 2);
                ss += __shfl_xor(ss, 4);
                ss += __shfl_xor(ss, 8);
                float inv = rsqrtf(ss);
                acc[as][0][r] *= inv;
                acc[as][1][r] *= inv;
            }
        }
    }

    #pragma unroll
    for (int as = 0; as < 2; as++) {
        #pragma unroll
        for (int bs = 0; bs < 2; bs++) {
            #pragma unroll
            for (int r = 0; r < 4; r++) {
                int Xrow = row0 + wm * 32 + as * 16 + lg * 4 + r;
                int c = col0 + wn * 32 + bs * 16 + l15;
                int n = Xrow >> 2, bb = Xrow & 3, hh = c >> 5, dd = c & 31;
                unsigned short val = f2b(acc[as][bs][r]);
                if (z == 0)      qb[((size_t)((bb * 8 + hh) * 1024 + n)) * 32 + dd] = val;
                else if (z == 1) kb[((size_t)((bb * 8 + hh) * 1024 + n)) * 32 + dd] = val;
                else             vt[((size_t)((bb * 8 + hh) * 32 + dd)) * 1024 + n] = val;
            }
        }
    }
}

// ---------------------------------------------------------------------------
// Kernel 2: position bias [H,N,N] -> bf16.  One thread per (n,m).
// No LDS: pw/pb read with wave-uniform indices -> s_load (SGPR operands);
// divides replaced by v_rcp muls; dual accumulators for the dot.
// ---------------------------------------------------------------------------
__global__ __launch_bounds__(256) void bias_kernel(
    const float* __restrict__ qbx, const float* __restrict__ kbx,
    const float* __restrict__ pw, const float* __restrict__ pb,
    unsigned short* __restrict__ biasb)
{
    int idx = blockIdx.x * 256 + threadIdx.x;
    int n = idx >> 10, m = idx & 1023;   // n uniform per block (4 blocks / n)

    float4 qx = ((const float4*)qbx)[n];
    float4 kx = ((const float4*)kbx)[m];

    float cx = 0.5f * (qx.x + qx.z), cy = 0.5f * (qx.y + qx.w);
    float bw = qx.z - qx.x + 1.0f,   bh = qx.w - qx.y + 1.0f;
    float cxr = 0.5f * (kx.x + kx.z), cyr = 0.5f * (kx.y + kx.w);
    float wr  = kx.z - kx.x + 1.0f,   hr  = kx.w - kx.y + 1.0f;

    float rbw = __builtin_amdgcn_rcpf(bw);
    float rbh = __builtin_amdgcn_rcpf(bh);
    float pm[4];
    pm[0] = __logf(fabsf((cx - cxr) * rbw) + 1e-3f);
    pm[1] = __logf(fabsf((cy - cyr) * rbh) + 1e-3f);
    pm[2] = __logf(bw * __builtin_amdgcn_rcpf(wr));
    pm[3] = __logf(bh * __builtin_amdgcn_rcpf(hr));

    const float inv[8] = {100.f, 42.1696503f, 17.7827941f, 7.49894209f,
                          3.16227766f, 1.33352143f, 0.562341325f, 0.237137371f};

    float emb[64];
    #pragma unroll
    for (int p = 0; p < 4; p++) {
        #pragma unroll
        for (int i = 0; i < 8; i++) {
            float a = pm[p] * inv[i];
            emb[p * 16 + i]     = __sinf(a);
            emb[p * 16 + 8 + i] = __cosf(a);
        }
    }

    #pragma unroll
    for (int h = 0; h < PH; h++) {
        float a0 = pb[h], a1 = 0.f;
        #pragma unroll
        for (int c4 = 0; c4 < 16; c4 += 2) {
            float4 w0 = ((const float4*)pw)[h * 16 + c4];
            float4 w1 = ((const float4*)pw)[h * 16 + c4 + 1];
            a0 += emb[c4 * 4 + 0] * w0.x + emb[c4 * 4 + 1] * w0.y
                + emb[c4 * 4 + 2] * w0.z + emb[c4 * 4 + 3] * w0.w;
            a1 += emb[c4 * 4 + 4] * w1.x + emb[c4 * 4 + 5] * w1.y
                + emb[c4 * 4 + 6] * w1.z + emb[c4 * 4 + 7] * w1.w;
        }
        float bv = __logf(fmaxf(a0 + a1, 0.f) + 1e-6f);
        biasb[((size_t)(h * 1024 + n)) * 1024 + m] = f2b(bv);
    }
}

// ---------------------------------------------------------------------------
// Kernel 3: fused attention (byte-identical to round 8).
// ---------------------------------------------------------------------------
#define SBS 1032   // bf16 elems per Sb row (2064 B, 16B-aligned rows)

__global__ __launch_bounds__(512, 4) void attn_kernel(
    const unsigned short* __restrict__ qb, const unsigned short* __restrict__ kb,
    const unsigned short* __restrict__ vt, const unsigned short* __restrict__ biasb,
    float* __restrict__ out, float* __restrict__ attn_out)
{
    __shared__ unsigned short Sb[16][SBS];        // 33024 B
    __shared__ float part[8][16][17];             // 8704 B

    const int bh = blockIdx.y;
    const int b = bh >> 3, h = bh & 7;
    const int n0 = blockIdx.x * 16;
    const int tid = threadIdx.x;
    const int w = tid >> 6, l = tid & 63;
    const int l15 = l & 15, lg = l >> 4;

    // ---- QK^T: wave w covers keys [w*128, w*128+128) = 8 MFMAs ----
    {
        const int qrow = n0 + l15;
        bf16x8 aq = *(const bf16x8*)(qb + ((size_t)(bh << 10) + qrow) * 32 + lg * 8);
        #pragma unroll
        for (int t = 0; t < 8; ++t) {
            int key = w * 128 + t * 16 + l15;
            bf16x8 bk = *(const bf16x8*)(kb + ((size_t)(bh << 10) + key) * 32 + lg * 8);
            f32x4 acc = (f32x4){0.f, 0.f, 0.f, 0.f};
            acc = __builtin_amdgcn_mfma_f32_16x16x32_bf16(aq, bk, acc, 0, 0, 0);
            #pragma unroll
            for (int r = 0; r < 4; ++r)
                Sb[lg * 4 + r][key] = f2b(acc[r]);
        }
    }
    __syncthreads();

    // ---- softmax + bias + attn write + P(bf16) back to LDS: 2 rows/wave ----
    {
        #pragma unroll
        for (int rr = 0; rr < 2; ++rr) {
            int r = w * 2 + rr;
            float s[16];
            #pragma unroll
            for (int i = 0; i < 16; ++i) s[i] = b2f(Sb[r][l + 64 * i]);
            float mx = s[0];
            #pragma unroll
            for (int i = 1; i < 16; ++i) mx = fmaxf(mx, s[i]);
            #pragma unroll
            for (int off = 32; off > 0; off >>= 1) mx = fmaxf(mx, __shfl_xor(mx, off));
            float e[16], sum = 0.f;
            #pragma unroll
            for (int i = 0; i < 16; ++i) { e[i] = __expf(s[i] - mx); sum += e[i]; }
            #pragma unroll
            for (int off = 32; off > 0; off >>= 1) sum += __shfl_xor(sum, off);
            float invs = 1.f / sum;

            const unsigned short* brow = biasb + ((size_t)(h * 1024 + n0 + r)) * 1024;
            float* arow = attn_out + ((size_t)(bh * 1024 + n0 + r)) * 1024;
            #pragma unroll
            for (int i = 0; i < 16; ++i) {
                int m = l + 64 * i;
                float a = e[i] * invs + b2f(brow[m]);
                arow[m] = a;
                Sb[r][m] = f2b(a);
            }
        }
    }
    __syncthreads();

    // ---- PV: wave = (ds = w>>2, kh = w&3); m-range kh*256..+256 ----
    {
        const int ds = w >> 2, kh = w & 3;
        f32x4 acc = (f32x4){0.f, 0.f, 0.f, 0.f};
        const unsigned short* vrow = vt + ((size_t)(bh * 32 + ds * 16 + l15) << 10);
        const unsigned short* srow = &Sb[l15][0];
        #pragma unroll
        for (int st = 0; st < 8; ++st) {
            int m0 = kh * 256 + st * 32 + lg * 8;
            bf16x8 ap = *(const bf16x8*)(srow + m0);
            bf16x8 bv = *(const bf16x8*)(vrow + m0);
            acc = __builtin_amdgcn_mfma_f32_16x16x32_bf16(ap, bv, acc, 0, 0, 0);
        }
        #pragma unroll
        for (int r = 0; r < 4; ++r) part[w][lg * 4 + r][l15] = acc[r];
    }
    __syncthreads();

    // ---- reduce k-quarters, write out [n][b][c] ----
    {
        int q = tid >> 5, d = tid & 31;
        int ds = d >> 4, d15 = d & 15;
        float v = part[ds * 4 + 0][q][d15] + part[ds * 4 + 1][q][d15]
                + part[ds * 4 + 2][q][d15] + part[ds * 4 + 3][q][d15];
        out[((size_t)(n0 + q) * PB + b) * PC + h * PD + d] = v;
    }
}

// ---------------------------------------------------------------------------
extern "C" void kernel_launch(void* const* d_in, const int* in_sizes, int n_in,
                              void* d_out, int out_size, void* d_ws, size_t ws_size,
                              hipStream_t stream)
{
    const float* query   = (const float*)d_in[0];
    const float* key     = (const float*)d_in[1];
    const float* value   = (const float*)d_in[2];
    const float* q_boxes = (const float*)d_in[3];
    const float* k_boxes = (const float*)d_in[4];
    const float* Wq      = (const float*)d_in[5];
    const float* Wk      = (const float*)d_in[6];
    const float* Wv      = (const float*)d_in[7];
    const float* pos_w   = (const float*)d_in[8];
    const float* pos_b   = (const float*)d_in[9];

    unsigned short* u = (unsigned short*)d_ws;
    unsigned short* qbf  = u;                     // 1048576 [bh][n][d] normalized
    unsigned short* kbf  = qbf + 1048576;         // 1048576 [bh][n][d] normalized
    unsigned short* vtb  = kbf + 1048576;         // 1048576 [bh][d][n]
    unsigned short* bias = vtb + 1048576;         // 8388608 [h][n][m]

    float* out  = (float*)d_out;                  // [N,B,C]
    float* attn = out + (size_t)PN * PB * PC;     // [B,H,N,N]

    proj_mfma<<<dim3(64, 4, 3), 256, 0, stream>>>(query, key, value, Wq, Wk, Wv,
                                                  qbf, kbf, vtb);
    bias_kernel<<<dim3(4096), 256, 0, stream>>>(q_boxes, k_boxes, pos_w, pos_b, bias);
    attn_kernel<<<dim3(64, 32), 512, 0, stream>>>(qbf, kbf, vtb, bias, out, attn);
}